// Round 9
// baseline (124.171 us; speedup 1.0000x reference)
//
#include <hip/hip_runtime.h>

#define KS   21
#define HH   48
#define WW   48
#define CC   3
#define ROW  (WW*CC)      /* 144 */
#define NB   4
#define NPIX (HH*WW*CC)   /* 6912 = 27*256 */
#define TPB  256
#define SEGS (NPIX/TPB)   /* 27 */
#define NBLK (NB*SEGS)    /* 108 */
#define TN   64           /* diff-table nodes over x in [0,1] */
#define CTAN 2.8853900817779268f   /* 2*log2(e) */
/* x in [0,1): tanh(x-b) == -1 (+/-6.7e-4) for all x if b >= 5; == +1 if b <= -4 */
#define B_HI 5.0f
#define B_LO -4.0f

__device__ __forceinline__ float fast_exp2(float x) {
#if __has_builtin(__builtin_amdgcn_exp2f)
    return __builtin_amdgcn_exp2f(x);
#else
    return __expf(x * 0.6931471805599453f);
#endif
}
__device__ __forceinline__ float fast_rcp(float x) {
#if __has_builtin(__builtin_amdgcn_rcpf)
    return __builtin_amdgcn_rcpf(x);
#else
    return 1.0f / x;
#endif
}

// 1D L2-normalized Gaussian tap (f,i). Outer product == reference's 2D
// L2-normalized kernel (amp cancels; 2D sum-sq factorizes into (1D sum-sq)^2).
__device__ __forceinline__ float tap1d(const float* g, int f, int i) {
    float sigma  = 1.0f / g[f];
    float inv2s2 = 0.5f / (sigma * sigma);
    const float step = 21.0f / 640.0f, mean = 21.0f / 64.0f;
    float r = (float)i * step - mean;
    float v = expf(-r * r * inv2s2);
    float ss = 0.0f;
    for (int j = 0; j < KS; ++j) {
        float rj = (float)j * step - mean;
        float vj = expf(-rj * rj * inv2s2);
        ss += vj * vj;
    }
    return v * rsqrtf(ss);
}

// Single plain dispatch; block (n,seg) owns 256 output pixels and holds the
// whole image privately in LDS:
//  P0 stage x + taps -> P1 h-conv(g) whole image -> P2 v-conv(g) whole image
//  + classify/compact into LDS list (LDS atomics only) + own-pixel direct 2D
//  m-conv (factored rows) -> P3 64-node tanh table, 4-way wave-split over the
//  compacted list -> P4 own-pixel direct 2D w-conv with table lerp -> store.
// No grid sync, no halo redundancy, no global scratch, d_ws unused.
__global__ __launch_bounds__(TPB) void inrf_one(
    const float* __restrict__ in, const float* __restrict__ gm,
    const float* __restrict__ gw, const float* __restrict__ gg,
    float* __restrict__ out)
{
    __shared__ float sx[NPIX];        // image (27.6 KB)
    __shared__ float sh[NPIX];        // h-conv(g) (27.6 KB)
    __shared__ float sl[NPIX];        // compacted CTAN*b list (worst case)
    __shared__ float part[4 * TN];
    __shared__ float gt[TN];
    __shared__ float st[189];         // taps: m [0,63) g [63,126) w [126,189)
    __shared__ int s_cnt, s_net;

    const int t   = threadIdx.x;
    const int blk = blockIdx.x;
    const int n   = blk / SEGS;
    const int seg = blk % SEGS;

    if (t == 0) { s_cnt = 0; s_net = 0; }
    if (t < 189) {
        int set = t / 63, f = (t % 63) / 21, i = t % 21;
        const float* g = (set == 0) ? gm : (set == 1) ? gg : gw;
        st[t] = tap1d(g, f, i);
    }
    const float* src = in + n * NPIX;
    for (int i = t; i < NPIX; i += TPB) sx[i] = src[i];
    __syncthreads();

    // ---- P1: horizontal conv (g) over the whole image ----
    for (int i = t; i < NPIX; i += TPB) {
        int c = i % CC, w = (i / CC) % WW;
        int rowb = i - w * CC;
        float a = 0.f;
#pragma unroll
        for (int k = 0; k < KS; ++k) {
            int wc  = w + k - 10;
            int wcc = min(max(wc, 0), WW - 1);
            bool ok = (unsigned)wc < (unsigned)WW;
            a = fmaf(sx[rowb + wcc * CC], ok ? st[63 + c * 21 + k] : 0.f, a);
        }
        sh[i] = a;
    }
    __syncthreads();

    // ---- P2: vertical conv (g) + classify/compact (ballots wave-uniform) ----
    const int lane = t & 63;
    const unsigned long long ltm = (1ull << lane) - 1ull;
    for (int i = t; i < NPIX; i += TPB) {       // uniform 27 iterations
        int c = i % CC, pos = i % ROW, h = i / ROW;
        float b = 0.f;
#pragma unroll
        for (int k = 0; k < KS; ++k) {
            int hc  = h + k - 10;
            int hcc = min(max(hc, 0), HH - 1);
            bool ok = (unsigned)hc < (unsigned)HH;
            b = fmaf(sh[hcc * ROW + pos], ok ? st[63 + c * 21 + k] : 0.f, b);
        }
        bool satneg = (b >= B_HI);              // tanh == -1 for all x
        bool satpos = (b <= B_LO);              // tanh == +1 for all x
        bool act = !(satneg || satpos);
        unsigned long long mb = __ballot(act);
        int cnt  = __popcll(mb);
        int netc = __popcll(__ballot(satpos)) - __popcll(__ballot(satneg));
        int base = 0;
        if (lane == 0) {
            if (cnt)  base = atomicAdd(&s_cnt, cnt);
            if (netc) atomicAdd(&s_net, netc);
        }
        base = __shfl(base, 0);
        if (act) sl[base + __popcll(mb & ltm)] = CTAN * b;
    }

    // own-pixel first term: direct 2D m-conv on sx (factored row sums).
    // Reads only sx (stable since P0 sync) -> legal before the next sync.
    const int own = seg * TPB + t;
    const int oc  = own % CC, ow = (own / CC) % WW, oh = own / ROW;
    float tM[KS];
#pragma unroll
    for (int k = 0; k < KS; ++k) tM[k] = st[oc * 21 + k];
    float firstv = 0.f;
    for (int kh = 0; kh < KS; ++kh) {
        int hc  = oh + kh - 10;
        int hcc = min(max(hc, 0), HH - 1);
        float mh = ((unsigned)hc < (unsigned)HH) ? tM[kh] : 0.f;
        int rowb = hcc * ROW + oc;
        float rs = 0.f;
#pragma unroll
        for (int kw = 0; kw < KS; ++kw) {
            int wc  = ow + kw - 10;
            int wcc = min(max(wc, 0), WW - 1);
            bool ok = (unsigned)wc < (unsigned)WW;
            rs = fmaf(sx[rowb + wcc * CC], ok ? tM[kw] : 0.f, rs);
        }
        firstv = fmaf(rs, mh, firstv);
    }
    __syncthreads();                            // list + counters complete

    // ---- P3: 64-node table, each node split across the 4 waves ----
    const int node  = t & (TN - 1);
    const int piece = t >> 6;                   // wave id 0..3
    const int len   = s_cnt;
    {
        const float cx = CTAN * ((float)node * (1.0f / (float)(TN - 1)));
        int q  = (len * piece) >> 2;
        int q1 = (len * (piece + 1)) >> 2;
        float a0 = 0.f, a1 = 0.f, a2 = 0.f, a3 = 0.f;
        for (; q + 3 < q1; q += 4) {
            a0 += fast_rcp(fast_exp2(cx - sl[q])     + 1.f);
            a1 += fast_rcp(fast_exp2(cx - sl[q + 1]) + 1.f);
            a2 += fast_rcp(fast_exp2(cx - sl[q + 2]) + 1.f);
            a3 += fast_rcp(fast_exp2(cx - sl[q + 3]) + 1.f);
        }
        for (; q < q1; ++q) a0 += fast_rcp(fast_exp2(cx - sl[q]) + 1.f);
        part[piece * TN + node] = (a0 + a1) + (a2 + a3);
    }
    __syncthreads();
    if (t < TN) {
        float s = part[t] + part[TN + t] + part[2 * TN + t] + part[3 * TN + t];
        gt[t] = ((float)(s_net + len) - 2.0f * s) * (1.0f / (float)NPIX);
    }
    __syncthreads();

    // ---- P4: own-pixel direct 2D w-conv of lerp(gt, x) + subtract ----
    float tW[KS];
#pragma unroll
    for (int k = 0; k < KS; ++k) tW[k] = st[126 + oc * 21 + k];
    float a = 0.f;
    for (int kh = 0; kh < KS; ++kh) {
        int hc  = oh + kh - 10;
        int hcc = min(max(hc, 0), HH - 1);
        float mh = ((unsigned)hc < (unsigned)HH) ? tW[kh] : 0.f;
        int rowb = hcc * ROW + oc;
        float rs = 0.f;
#pragma unroll
        for (int kw = 0; kw < KS; ++kw) {
            int wc  = ow + kw - 10;
            int wcc = min(max(wc, 0), WW - 1);
            bool ok = (unsigned)wc < (unsigned)WW;
            float xv = sx[rowb + wcc * CC];
            float u  = xv * (float)(TN - 1);
            u = fminf(fmaxf(u, 0.0f), (float)(TN - 1) - 1.0001f);
            int   ii = (int)u;
            float fr = u - (float)ii;
            float gv = fmaf(fr, gt[ii + 1] - gt[ii], gt[ii]);
            rs = fmaf(gv, ok ? tW[kw] : 0.f, rs);
        }
        a = fmaf(rs, mh, a);
    }
    out[n * NPIX + own] = firstv - a;
}

extern "C" void kernel_launch(void* const* d_in, const int* in_sizes, int n_in,
                              void* d_out, int out_size, void* d_ws, size_t ws_size,
                              hipStream_t stream) {
    const float* in = (const float*)d_in[0];
    const float* gm = (const float*)d_in[1];
    const float* gw = (const float*)d_in[2];
    const float* gg = (const float*)d_in[3];
    float* out = (float*)d_out;
    (void)d_ws; (void)ws_size;

    inrf_one<<<NBLK, TPB, 0, stream>>>(in, gm, gw, gg, out);
}